// Round 12
// baseline (40.535 us; speedup 1.0000x reference)
//
#include <hip/hip_runtime.h>
#include <math.h>

#define D_ 512
#define H_ 8
#define I_ 64
#define L_ 1024

typedef __attribute__((ext_vector_type(8))) short short8;
typedef __attribute__((ext_vector_type(4))) float f32x4;

__device__ __forceinline__ float sigmoidf_(float x) { return 1.f / (1.f + expf(-x)); }
__device__ __forceinline__ float siluf_(float x) { return x / (1.f + expf(-x)); }

__device__ __forceinline__ unsigned short f2bf(float f) {
    unsigned u = __float_as_uint(f);
    u += 0x7fffu + ((u >> 16) & 1u);   // round-to-nearest-even
    return (unsigned short)(u >> 16);
}
__device__ __forceinline__ float bf2f(unsigned short v) {
    return __uint_as_float((unsigned)v << 16);
}

// Staging tiles are [64 rows][32 k] bf16 with 80B row stride (64B rows alias banks
// every 2 rows -> 8-way b128 conflicts, R8/R9: 2.77M cycles; 80B -> 2-way, free).
#define RS 80        // row stride in bytes
#define RSS 40       // row stride in shorts

// ========== K1: 4x W transpose (256 blocks) + angabs heads + xb bf16 (BL/4 blocks) ==========
__global__ __launch_bounds__(256) void k1_prep(
    const float* __restrict__ x, unsigned short* __restrict__ xb,
    const float* __restrict__ w0, const float* __restrict__ w1,
    const float* __restrict__ w2, const float* __restrict__ w3,
    unsigned short* __restrict__ t0, unsigned short* __restrict__ t1,
    unsigned short* __restrict__ t2, unsigned short* __restrict__ t3,
    const float* __restrict__ w_ang, const float* __restrict__ b_ang,
    const float* __restrict__ w_abs, const float* __restrict__ b_abs,
    float* __restrict__ a_out, float* __restrict__ r_out)
{
    __shared__ float sm[64][65];
    const int tid = threadIdx.x;
    const int bid = blockIdx.x;
    if (bid < 256) {
        // ---- W[k][n] -> Wt[n][k] bf16 ----
        int zsel = bid >> 6, tile = bid & 63;
        const float* src = zsel == 0 ? w0 : zsel == 1 ? w1 : zsel == 2 ? w2 : w3;
        unsigned short* dst = zsel == 0 ? t0 : zsel == 1 ? t1 : zsel == 2 ? t2 : t3;
        const int k0 = (tile >> 3) * 64, n0 = (tile & 7) * 64;
#pragma unroll
        for (int i = 0; i < 16; ++i) {
            int idx = tid + i * 256;
            int rr = idx >> 6, cc = idx & 63;
            sm[rr][cc] = src[(size_t)(k0 + rr) * 512 + n0 + cc];
        }
        __syncthreads();
#pragma unroll
        for (int i = 0; i < 16; ++i) {
            int idx = tid + i * 256;
            int rr = idx >> 6, cc = idx & 63;   // rr = n-local, cc = k-local
            dst[(size_t)(n0 + rr) * 512 + k0 + cc] = f2bf(sm[cc][rr]);
        }
        return;
    }
    // ---- angabs + xb: stage 4 rows in LDS, emit bf16 x, compute head dots from LDS ----
    {
        float* xs = &sm[0][0];                 // 2048 floats (fits in sm)
        const int t = bid - 256;
        const int n0 = t * 4;
#pragma unroll
        for (int p = 0; p < 2; ++p) {
            int idx = (p * 256 + tid) * 4;     // 0..2047 floats
            int rr = idx >> 9, cc = idx & 511;
            float4 v = *(const float4*)(x + (size_t)(n0 + rr) * 512 + cc);
            *(float4*)(xs + idx) = v;
            ushort4 o = { f2bf(v.x), f2bf(v.y), f2bf(v.z), f2bf(v.w) };
            *(ushort4*)(xb + (size_t)(n0 + rr) * 512 + cc) = o;
        }
        __syncthreads();
        const int s = tid & 3, c = (tid >> 2) & 15, r = tid >> 6;
        const int h = c & 7;
        const float* wp = (c < 8) ? w_ang : w_abs;
        const float* xr = xs + r * 512;
        float acc = 0.f;
#pragma unroll 4
        for (int i = 0; i < 128; ++i) {
            int k = i * 4 + s;
            acc = fmaf(xr[k], wp[k * H_ + h], acc);
        }
        acc += __shfl_xor(acc, 1);
        acc += __shfl_xor(acc, 2);
        if (s == 0) {
            const int n = n0 + r;
            const float scale = expf(-6.9077552789821368f * (h * (1.0f / 7.0f)));  // 0.001^(h/7)
            if (c < 8) { float p = acc + b_ang[h]; a_out[(size_t)n * H_ + h] = siluf_(p) * scale; }
            else       { float p = acc + b_abs[h]; r_out[(size_t)n * H_ + h] = sigmoidf_(p) * scale; }
        }
    }
}

// ===== K2: split GEMM families (2 blocks/CU), A = pre-converted bf16 (pure int4 staging) =====
// grid = 16 + 256 + 256:
//   bids [0,16):    scan riders; [16,272): z/za -> Zs_part,zdiag; [272,528): ya -> gateb
// XCD remap: same-rblk blocks share bid%8 -> x panel read once per XCD.
__global__ __launch_bounds__(256) void k2_split(
    const unsigned short* __restrict__ xb,
    const unsigned short* __restrict__ Wz, const unsigned short* __restrict__ Wza,
    const unsigned short* __restrict__ Wya,
    const float* __restrict__ b_z, const float* __restrict__ b_za, const float* __restrict__ b_ya,
    unsigned short* __restrict__ gateb, float* __restrict__ Zs_part, float* __restrict__ zdiag,
    const float* __restrict__ a_arr, const float* __restrict__ r_arr,
    float* __restrict__ Si, float* __restrict__ Sr)
{
    __shared__ short As[2][64 * RSS];
    __shared__ short Bs[2][2][64 * RSS];
    __shared__ float red[64][8];
    __shared__ float2 buf[2][256];
    const int tid = threadIdx.x;
    const int bid = blockIdx.x;

    if (bid < 16) {
        // ---------- scan rider: inclusive cumsum over l for one (b,h) ----------
        const int b = bid >> 3, h = bid & 7;
        float2 v[4];
        float2 run = make_float2(0.f, 0.f);
        const size_t base = ((size_t)b * L_ + tid * 4) * H_ + h;
#pragma unroll
        for (int j = 0; j < 4; ++j) {
            run.x += a_arr[base + j * H_];
            run.y += r_arr[base + j * H_];
            v[j] = run;
        }
        buf[0][tid] = run;
        __syncthreads();
        int src = 0;
        for (int off = 1; off < 256; off <<= 1) {
            float2 val = buf[src][tid];
            if (tid >= off) { float2 q = buf[src][tid - off]; val.x += q.x; val.y += q.y; }
            buf[src ^ 1][tid] = val;
            src ^= 1;
            __syncthreads();
        }
        float2 excl = make_float2(0.f, 0.f);
        if (tid > 0) excl = buf[src][tid - 1];
#pragma unroll
        for (int j = 0; j < 4; ++j) {
            Si[base + j * H_] = v[j].x + excl.x;
            Sr[base + j * H_] = -(v[j].y + excl.y);
        }
        return;
    }

    const bool zza = bid < 272;
    const int u = zza ? (bid - 16) : (bid - 272);   // 0..255 (both offsets %8 == 0)
    const int rblk = (u & 7) * 4 + (u >> 6);        // same rblk -> same bid%8 -> same XCD
    const int bx = (u >> 3) & 7;                    // col panel == head
    const int lane = tid & 63, w = tid >> 6;
    const int wm = w >> 1, wn = w & 1;
    const int row0 = rblk * 64, col0 = bx * 64;

    const f32x4 zf = {0.f, 0.f, 0.f, 0.f};
    const int sr_ = tid >> 2, sc_ = tid & 3;
    const int sld = sr_ * RS + sc_ * 16;            // padded-stride LDS byte offset
    const unsigned short* gXa = xb + (size_t)(row0 + sr_) * 512 + sc_ * 8;
    const int ck = (lane >> 4) << 4;                // 16B chunk within row

    if (zza) {
        // ================= z/za family =================
        const unsigned short* gWz  = Wz  + (size_t)(col0 + sr_) * 512 + sc_ * 8;
        const unsigned short* gWza = Wza + (size_t)(col0 + sr_) * 512 + sc_ * 8;
        f32x4 accz[2][2], accza[2][2];
#pragma unroll
        for (int a = 0; a < 2; ++a)
#pragma unroll
            for (int bq = 0; bq < 2; ++bq) { accz[a][bq] = zf; accza[a][bq] = zf; }

        int4 rxa, rz, rza;
#define Z_LOAD(K) { rxa = *(const int4*)(gXa + (K)); \
                    rz  = *(const int4*)(gWz  + (K)); rza = *(const int4*)(gWza + (K)); }
#define Z_WRITE(BUF) { *(int4*)((char*)As[BUF] + sld) = rxa; \
                       *(int4*)((char*)Bs[BUF][0] + sld) = rz; \
                       *(int4*)((char*)Bs[BUF][1] + sld) = rza; }

        Z_LOAD(0);
        Z_WRITE(0);
        Z_LOAD(32);
        __syncthreads();

        int cur = 0;
        for (int s = 0; s < 16; ++s) {
            if (s < 15) {
                Z_WRITE(cur ^ 1);
                if (s < 14) Z_LOAD((s + 2) * 32);
            }
            short8 af[2], bz[2], bza[2];
#pragma unroll
            for (int fi = 0; fi < 2; ++fi) {
                int rr = wm * 32 + fi * 16 + (lane & 15);
                af[fi] = *(const short8*)((const char*)As[cur] + rr * RS + ck);
            }
#pragma unroll
            for (int fj = 0; fj < 2; ++fj) {
                int rr = wn * 32 + fj * 16 + (lane & 15);
                bz[fj]  = *(const short8*)((const char*)Bs[cur][0] + rr * RS + ck);
                bza[fj] = *(const short8*)((const char*)Bs[cur][1] + rr * RS + ck);
            }
#pragma unroll
            for (int fi = 0; fi < 2; ++fi)
#pragma unroll
                for (int fj = 0; fj < 2; ++fj) {
                    accz[fi][fj]  = __builtin_amdgcn_mfma_f32_16x16x32_bf16(af[fi], bz[fj],  accz[fi][fj],  0, 0, 0);
                    accza[fi][fj] = __builtin_amdgcn_mfma_f32_16x16x32_bf16(af[fi], bza[fj], accza[fi][fj], 0, 0, 0);
                }
            __syncthreads();
            cur ^= 1;
        }
#undef Z_LOAD
#undef Z_WRITE

        const bool first = (rblk & 15) == 0;       // rows l in [0,64): contains l<=h and diag
        const int b8 = (rblk >> 4) * 8;
#pragma unroll
        for (int fj = 0; fj < 2; ++fj) {
            float lsum = 0.f;
            int lc = wn * 32 + fj * 16 + (lane & 15);
            int col = col0 + lc;
            float Bz = b_z[col], Bza = b_za[col];
#pragma unroll
            for (int fi = 0; fi < 2; ++fi) {
#pragma unroll
                for (int q = 0; q < 4; ++q) {
                    int lr = wm * 32 + fi * 16 + ((lane >> 4) << 2) + q;
                    float pz = accz[fi][fj][q] + Bz;
                    float pza = accza[fi][fj][q] + Bza;
                    float v = pz * siluf_(pza);
                    if (!first || lr > bx) lsum += v;
                    if (first && lr == bx) zdiag[(b8 + bx) * 64 + lc] = v;
                }
            }
            red[lc][wm * 4 + (lane >> 4)] = lsum;
        }
        __syncthreads();
        if (tid < 64) {
            float s = 0.f;
#pragma unroll
            for (int j = 0; j < 8; ++j) s += red[tid][j];
            Zs_part[((size_t)rblk * 8 + bx) * 64 + tid] = s;   // race-free partials
        }
    } else {
        // ================= ya family (gate) =================
        const unsigned short* gWya = Wya + (size_t)(col0 + sr_) * 512 + sc_ * 8;
        f32x4 accya[2][2];
#pragma unroll
        for (int a = 0; a < 2; ++a)
#pragma unroll
            for (int bq = 0; bq < 2; ++bq) accya[a][bq] = zf;

        int4 rxa, rya;
#define Y_LOAD(K) { rxa = *(const int4*)(gXa + (K)); rya = *(const int4*)(gWya + (K)); }
#define Y_WRITE(BUF) { *(int4*)((char*)As[BUF] + sld) = rxa; \
                       *(int4*)((char*)Bs[BUF][0] + sld) = rya; }

        Y_LOAD(0);
        Y_WRITE(0);
        Y_LOAD(32);
        __syncthreads();

        int cur = 0;
        for (int s = 0; s < 16; ++s) {
            if (s < 15) {
                Y_WRITE(cur ^ 1);
                if (s < 14) Y_LOAD((s + 2) * 32);
            }
            short8 af[2], bya[2];
#pragma unroll
            for (int fi = 0; fi < 2; ++fi) {
                int rr = wm * 32 + fi * 16 + (lane & 15);
                af[fi] = *(const short8*)((const char*)As[cur] + rr * RS + ck);
            }
#pragma unroll
            for (int fj = 0; fj < 2; ++fj) {
                int rr = wn * 32 + fj * 16 + (lane & 15);
                bya[fj] = *(const short8*)((const char*)Bs[cur][0] + rr * RS + ck);
            }
#pragma unroll
            for (int fi = 0; fi < 2; ++fi)
#pragma unroll
                for (int fj = 0; fj < 2; ++fj)
                    accya[fi][fj] = __builtin_amdgcn_mfma_f32_16x16x32_bf16(af[fi], bya[fj], accya[fi][fj], 0, 0, 0);
            __syncthreads();
            cur ^= 1;
        }
#undef Y_LOAD
#undef Y_WRITE

#pragma unroll
        for (int fj = 0; fj < 2; ++fj) {
            int lc = wn * 32 + fj * 16 + (lane & 15);
            int col = col0 + lc;
            float Bya = b_ya[col];
#pragma unroll
            for (int fi = 0; fi < 2; ++fi)
#pragma unroll
                for (int q = 0; q < 4; ++q) {
                    int lr = wm * 32 + fi * 16 + ((lane >> 4) << 2) + q;
                    int row = row0 + lr;
                    gateb[(size_t)row * 512 + col] = f2bf(siluf_(accya[fi][fj][q] + Bya));
                }
        }
    }
}

// ========== K3: 32-row blocks (3 blocks/CU): inline hgn -> LDS bf16 + reg-pipelined gemm_y ====
// grid = 512: cbx = bid&7 (same-Wy-panel per XCD), rsub = bid>>3 (0..63), row0 = rsub*32.
__global__ __launch_bounds__(256) void k3_hgn_gemm_y(
    const unsigned short* __restrict__ Wy, const float* __restrict__ b_y,
    const unsigned short* __restrict__ gateb,
    const float* __restrict__ Sr, const float* __restrict__ Si,
    const float* __restrict__ Zs_part, const float* __restrict__ zdiag,
    const float* __restrict__ lc_r, const float* __restrict__ lc_i,
    const float* __restrict__ gn_w, const float* __restrict__ gn_b,
    float* __restrict__ y)
{
    __shared__ unsigned short hA[32][520];          // 1040B row stride (period-8 slot cycle)
    __shared__ short Bs[2][64 * RSS];
    __shared__ float Cr[8][65], Ci[8][65], Zd[8][65];
    const int tid = threadIdx.x;
    const int lane = tid & 63, w = tid >> 6;
    const int cbx = blockIdx.x & 7;
    const int rsub = blockIdx.x >> 3;               // 0..63
    const int row0 = rsub * 32, col0 = cbx * 64;
    const int b = row0 >> 10;                       // L_=1024

    // ---- prologue: issue Wy tiles 0 and 1 into regs; latency hides under hgn phase ----
    const int brow = tid >> 2, bsc = tid & 3;       // 64 rows x 4 chunks of 16B
    const size_t gB = (size_t)(col0 + brow) * 512 + bsc * 8;
    const int bwr = brow * RS + bsc * 16;
    int4 rw0 = *(const int4*)(Wy + gB);
    int4 rw1 = *(const int4*)(Wy + gB + 32);

    // ---- stage per-(h,i) constants: Zs (reduced from partials) + lc, zdiag ----
    for (int uu = tid; uu < 512; uu += 256) {
        int h = uu >> 6, i = uu & 63;
        float s = 0.f;
#pragma unroll
        for (int rb = 0; rb < 16; ++rb)
            s += Zs_part[(((size_t)b * 16 + rb) * 8 + h) * 64 + i];
        Cr[h][i] = s + lc_r[h * 64 + i];
        Ci[h][i] = lc_i[h * 64 + i];
        Zd[h][i] = zdiag[((size_t)b * 8 + h) * 64 + i];
    }
    __syncthreads();

    // ---- phase 1: h + GroupNorm, one (row, head) per thread, write bf16 into hA ----
    {
        const int r = tid >> 3, h = tid & 7;        // r in 0..31
        const int row = row0 + r;
        const float sr = Sr[(size_t)row * 8 + h];
        const float si = Si[(size_t)row * 8 + h];
        const float er = expf(sr);
        const float ca = er * cosf(si), sb = er * sinf(si);
        float sum = 0.f, sq = 0.f;
#pragma unroll 8
        for (int i = 0; i < 64; ++i) {
            float hv = Zd[h][i] + ca * Cr[h][i] - sb * Ci[h][i];
            sum += hv; sq += hv * hv;
        }
        const float mean = sum * (1.f / 64.f);
        const float inv = rsqrtf(sq * (1.f / 64.f) - mean * mean + 1e-5f);
        const float gw = gn_w[h] * inv;
        const float gb = gn_b[h] - mean * gw;
#pragma unroll
        for (int s8 = 0; s8 < 8; ++s8) {
            short8 pk;
#pragma unroll
            for (int j = 0; j < 8; ++j) {
                int i = s8 * 8 + j;
                float hv = Zd[h][i] + ca * Cr[h][i] - sb * Ci[h][i];
                pk[j] = (short)f2bf(hv * gw + gb);
            }
            int slot = (s8 + h) & 7;   // per-head slot rotation: conflict-free writes
            *(short8*)((char*)&hA[r][0] + h * 128 + slot * 16) = pk;
        }
    }
    *(int4*)((char*)Bs[0] + bwr) = rw0;             // stage Wy tile 0
    __syncthreads();

    // ---- phase 2: y = (hA @ Wy^T(bf16) + b_y) * gate, reg-pipelined Wy, 4 col-quarter waves --
    const f32x4 zf = {0.f, 0.f, 0.f, 0.f};
    f32x4 acc[2] = {zf, zf};

    int cur = 0;
    for (int s = 0; s < 16; ++s) {
        if (s < 15) {
            *(int4*)((char*)Bs[cur ^ 1] + bwr) = rw1;               // stage tile s+1
            if (s < 14) rw1 = *(const int4*)(Wy + gB + (s + 2) * 32);   // prefetch s+2
        }
        const int k0 = s * 32;
        short8 af[2], bf;
        const int hk = k0 >> 6;
        const int t = ((k0 & 32) >> 3) + (lane >> 4);
        const int slot = (t + hk) & 7;              // undo phase-1 rotation
#pragma unroll
        for (int fi = 0; fi < 2; ++fi) {
            int rr = fi * 16 + (lane & 15);
            af[fi] = *(const short8*)((const char*)&hA[rr][0] + hk * 128 + slot * 16);
        }
        {
            int rr = w * 16 + (lane & 15);
            bf = *(const short8*)((const char*)Bs[cur] + rr * RS + ((lane >> 4) << 4));
        }
        acc[0] = __builtin_amdgcn_mfma_f32_16x16x32_bf16(af[0], bf, acc[0], 0, 0, 0);
        acc[1] = __builtin_amdgcn_mfma_f32_16x16x32_bf16(af[1], bf, acc[1], 0, 0, 0);
        __syncthreads();
        cur ^= 1;
    }

    const int col = col0 + w * 16 + (lane & 15);
    const float By = b_y[col];
#pragma unroll
    for (int fi = 0; fi < 2; ++fi)
#pragma unroll
        for (int q = 0; q < 4; ++q) {
            int row = row0 + fi * 16 + ((lane >> 4) << 2) + q;
            size_t idx = (size_t)row * 512 + col;
            y[idx] = (acc[fi][q] + By) * bf2f(gateb[idx]);
        }
}

extern "C" void kernel_launch(void* const* d_in, const int* in_sizes, int n_in,
                              void* d_out, int out_size, void* d_ws, size_t ws_size,
                              hipStream_t stream) {
    (void)n_in; (void)out_size; (void)ws_size;
    const float* x     = (const float*)d_in[0];
    const float* w_z   = (const float*)d_in[1];
    const float* b_z   = (const float*)d_in[2];
    const float* w_za  = (const float*)d_in[3];
    const float* b_za  = (const float*)d_in[4];
    const float* w_ang = (const float*)d_in[5];
    const float* b_ang = (const float*)d_in[6];
    const float* w_abs = (const float*)d_in[7];
    const float* b_abs = (const float*)d_in[8];
    const float* w_y   = (const float*)d_in[9];
    const float* b_y   = (const float*)d_in[10];
    const float* w_ya  = (const float*)d_in[11];
    const float* b_ya  = (const float*)d_in[12];
    const float* gn_w  = (const float*)d_in[13];
    const float* gn_b  = (const float*)d_in[14];
    const float* lc_r  = (const float*)d_in[15];
    const float* lc_i  = (const float*)d_in[16];
    float* y = (float*)d_out;

    const int BL = in_sizes[0] / D_;   // 2048
    const int B  = BL / L_;            // 2

    unsigned short* wtz  = (unsigned short*)d_ws;            // 512*512 each
    unsigned short* wtza = wtz  + 512 * 512;
    unsigned short* wtya = wtza + 512 * 512;
    unsigned short* wty  = wtya + 512 * 512;
    unsigned short* gateb= wty  + 512 * 512;                 // BL*512
    unsigned short* xb   = gateb + (size_t)BL * 512;         // BL*512 bf16
    float* a_arr = (float*)(xb + (size_t)BL * 512);          // BL*H
    float* r_arr = a_arr + (size_t)BL * H_;
    float* Si    = r_arr + (size_t)BL * H_;
    float* Sr    = Si    + (size_t)BL * H_;
    float* zdiag = Sr    + (size_t)BL * H_;                  // B*H*I
    float* Zs_part = zdiag + (size_t)B * H_ * I_;            // (BL/64)*H*I

    const int ntiles = (BL / 64) * 8;       // 256

    k1_prep<<<256 + BL / 4, 256, 0, stream>>>(
        x, xb, w_z, w_za, w_ya, w_y, wtz, wtza, wtya, wty,
        w_ang, b_ang, w_abs, b_abs, a_arr, r_arr);
    k2_split<<<16 + 2 * ntiles, 256, 0, stream>>>(
        xb, wtz, wtza, wtya, b_z, b_za, b_ya,
        gateb, Zs_part, zdiag, a_arr, r_arr, Si, Sr);
    k3_hgn_gemm_y<<<2 * ntiles, 256, 0, stream>>>(
        wty, b_y, gateb, Sr, Si, Zs_part, zdiag, lc_r, lc_i, gn_w, gn_b, y);
}

// Round 13
// 39.839 us; speedup vs baseline: 1.0175x; 1.0175x over previous
//
#include <hip/hip_runtime.h>
#include <math.h>

#define D_ 512
#define H_ 8
#define I_ 64
#define L_ 1024

typedef __attribute__((ext_vector_type(8))) short short8;
typedef __attribute__((ext_vector_type(4))) float f32x4;

__device__ __forceinline__ float sigmoidf_(float x) { return 1.f / (1.f + expf(-x)); }
__device__ __forceinline__ float siluf_(float x) { return x / (1.f + expf(-x)); }

__device__ __forceinline__ unsigned short f2bf(float f) {
    unsigned u = __float_as_uint(f);
    u += 0x7fffu + ((u >> 16) & 1u);   // round-to-nearest-even
    return (unsigned short)(u >> 16);
}
__device__ __forceinline__ float bf2f(unsigned short v) {
    return __uint_as_float((unsigned)v << 16);
}

// Staging tiles are [64 rows][32 k] bf16 with 80B row stride (64B rows alias banks
// every 2 rows -> 8-way b128 conflicts, R8/R9: 2.77M cycles; 80B -> 2-way, free).
#define RS 80        // row stride in bytes
#define RSS 40       // row stride in shorts

// ========== K1: 4x W transpose (256 blocks) + angabs heads + xb bf16 (BL/4 blocks) ==========
__global__ __launch_bounds__(256) void k1_prep(
    const float* __restrict__ x, unsigned short* __restrict__ xb,
    const float* __restrict__ w0, const float* __restrict__ w1,
    const float* __restrict__ w2, const float* __restrict__ w3,
    unsigned short* __restrict__ t0, unsigned short* __restrict__ t1,
    unsigned short* __restrict__ t2, unsigned short* __restrict__ t3,
    const float* __restrict__ w_ang, const float* __restrict__ b_ang,
    const float* __restrict__ w_abs, const float* __restrict__ b_abs,
    float* __restrict__ a_out, float* __restrict__ r_out)
{
    __shared__ float sm[64][65];
    const int tid = threadIdx.x;
    const int bid = blockIdx.x;
    if (bid < 256) {
        // ---- W[k][n] -> Wt[n][k] bf16 ----
        int zsel = bid >> 6, tile = bid & 63;
        const float* src = zsel == 0 ? w0 : zsel == 1 ? w1 : zsel == 2 ? w2 : w3;
        unsigned short* dst = zsel == 0 ? t0 : zsel == 1 ? t1 : zsel == 2 ? t2 : t3;
        const int k0 = (tile >> 3) * 64, n0 = (tile & 7) * 64;
#pragma unroll
        for (int i = 0; i < 16; ++i) {
            int idx = tid + i * 256;
            int rr = idx >> 6, cc = idx & 63;
            sm[rr][cc] = src[(size_t)(k0 + rr) * 512 + n0 + cc];
        }
        __syncthreads();
#pragma unroll
        for (int i = 0; i < 16; ++i) {
            int idx = tid + i * 256;
            int rr = idx >> 6, cc = idx & 63;   // rr = n-local, cc = k-local
            dst[(size_t)(n0 + rr) * 512 + k0 + cc] = f2bf(sm[cc][rr]);
        }
        return;
    }
    // ---- angabs + xb: stage 4 rows in LDS, emit bf16 x, compute head dots from LDS ----
    {
        float* xs = &sm[0][0];                 // 2048 floats (fits in sm)
        const int t = bid - 256;
        const int n0 = t * 4;
#pragma unroll
        for (int p = 0; p < 2; ++p) {
            int idx = (p * 256 + tid) * 4;     // 0..2047 floats
            int rr = idx >> 9, cc = idx & 511;
            float4 v = *(const float4*)(x + (size_t)(n0 + rr) * 512 + cc);
            *(float4*)(xs + idx) = v;
            ushort4 o = { f2bf(v.x), f2bf(v.y), f2bf(v.z), f2bf(v.w) };
            *(ushort4*)(xb + (size_t)(n0 + rr) * 512 + cc) = o;
        }
        __syncthreads();
        const int s = tid & 3, c = (tid >> 2) & 15, r = tid >> 6;
        const int h = c & 7;
        const float* wp = (c < 8) ? w_ang : w_abs;
        const float* xr = xs + r * 512;
        float acc = 0.f;
#pragma unroll 4
        for (int i = 0; i < 128; ++i) {
            int k = i * 4 + s;
            acc = fmaf(xr[k], wp[k * H_ + h], acc);
        }
        acc += __shfl_xor(acc, 1);
        acc += __shfl_xor(acc, 2);
        if (s == 0) {
            const int n = n0 + r;
            const float scale = expf(-6.9077552789821368f * (h * (1.0f / 7.0f)));  // 0.001^(h/7)
            if (c < 8) { float p = acc + b_ang[h]; a_out[(size_t)n * H_ + h] = siluf_(p) * scale; }
            else       { float p = acc + b_abs[h]; r_out[(size_t)n * H_ + h] = sigmoidf_(p) * scale; }
        }
    }
}

// ===== K2: split GEMM families (2 blocks/CU), A = pre-converted bf16 (pure int4 staging) =====
// grid = 16 + 256 + 256:
//   bids [0,16):    scan riders; [16,272): z/za -> Zs_part,zdiag; [272,528): ya -> gateb
// XCD remap: same-rblk blocks share bid%8 -> x panel read once per XCD.
__global__ __launch_bounds__(256) void k2_split(
    const unsigned short* __restrict__ xb,
    const unsigned short* __restrict__ Wz, const unsigned short* __restrict__ Wza,
    const unsigned short* __restrict__ Wya,
    const float* __restrict__ b_z, const float* __restrict__ b_za, const float* __restrict__ b_ya,
    unsigned short* __restrict__ gateb, float* __restrict__ Zs_part, float* __restrict__ zdiag,
    const float* __restrict__ a_arr, const float* __restrict__ r_arr,
    float* __restrict__ Si, float* __restrict__ Sr)
{
    __shared__ short As[2][64 * RSS];
    __shared__ short Bs[2][2][64 * RSS];
    __shared__ float red[64][8];
    __shared__ float2 buf[2][256];
    const int tid = threadIdx.x;
    const int bid = blockIdx.x;

    if (bid < 16) {
        // ---------- scan rider: inclusive cumsum over l for one (b,h) ----------
        const int b = bid >> 3, h = bid & 7;
        float2 v[4];
        float2 run = make_float2(0.f, 0.f);
        const size_t base = ((size_t)b * L_ + tid * 4) * H_ + h;
#pragma unroll
        for (int j = 0; j < 4; ++j) {
            run.x += a_arr[base + j * H_];
            run.y += r_arr[base + j * H_];
            v[j] = run;
        }
        buf[0][tid] = run;
        __syncthreads();
        int src = 0;
        for (int off = 1; off < 256; off <<= 1) {
            float2 val = buf[src][tid];
            if (tid >= off) { float2 q = buf[src][tid - off]; val.x += q.x; val.y += q.y; }
            buf[src ^ 1][tid] = val;
            src ^= 1;
            __syncthreads();
        }
        float2 excl = make_float2(0.f, 0.f);
        if (tid > 0) excl = buf[src][tid - 1];
#pragma unroll
        for (int j = 0; j < 4; ++j) {
            Si[base + j * H_] = v[j].x + excl.x;
            Sr[base + j * H_] = -(v[j].y + excl.y);
        }
        return;
    }

    const bool zza = bid < 272;
    const int u = zza ? (bid - 16) : (bid - 272);   // 0..255 (both offsets %8 == 0)
    const int rblk = (u & 7) * 4 + (u >> 6);        // same rblk -> same bid%8 -> same XCD
    const int bx = (u >> 3) & 7;                    // col panel == head
    const int lane = tid & 63, w = tid >> 6;
    const int wm = w >> 1, wn = w & 1;
    const int row0 = rblk * 64, col0 = bx * 64;

    const f32x4 zf = {0.f, 0.f, 0.f, 0.f};
    const int sr_ = tid >> 2, sc_ = tid & 3;
    const int sld = sr_ * RS + sc_ * 16;            // padded-stride LDS byte offset
    const unsigned short* gXa = xb + (size_t)(row0 + sr_) * 512 + sc_ * 8;
    const int ck = (lane >> 4) << 4;                // 16B chunk within row

    if (zza) {
        // ================= z/za family =================
        const unsigned short* gWz  = Wz  + (size_t)(col0 + sr_) * 512 + sc_ * 8;
        const unsigned short* gWza = Wza + (size_t)(col0 + sr_) * 512 + sc_ * 8;
        f32x4 accz[2][2], accza[2][2];
#pragma unroll
        for (int a = 0; a < 2; ++a)
#pragma unroll
            for (int bq = 0; bq < 2; ++bq) { accz[a][bq] = zf; accza[a][bq] = zf; }

        int4 rxa, rz, rza;
#define Z_LOAD(K) { rxa = *(const int4*)(gXa + (K)); \
                    rz  = *(const int4*)(gWz  + (K)); rza = *(const int4*)(gWza + (K)); }
#define Z_WRITE(BUF) { *(int4*)((char*)As[BUF] + sld) = rxa; \
                       *(int4*)((char*)Bs[BUF][0] + sld) = rz; \
                       *(int4*)((char*)Bs[BUF][1] + sld) = rza; }

        Z_LOAD(0);
        Z_WRITE(0);
        Z_LOAD(32);
        __syncthreads();

        int cur = 0;
        for (int s = 0; s < 16; ++s) {
            if (s < 15) {
                Z_WRITE(cur ^ 1);
                if (s < 14) Z_LOAD((s + 2) * 32);
            }
            short8 af[2], bz[2], bza[2];
#pragma unroll
            for (int fi = 0; fi < 2; ++fi) {
                int rr = wm * 32 + fi * 16 + (lane & 15);
                af[fi] = *(const short8*)((const char*)As[cur] + rr * RS + ck);
            }
#pragma unroll
            for (int fj = 0; fj < 2; ++fj) {
                int rr = wn * 32 + fj * 16 + (lane & 15);
                bz[fj]  = *(const short8*)((const char*)Bs[cur][0] + rr * RS + ck);
                bza[fj] = *(const short8*)((const char*)Bs[cur][1] + rr * RS + ck);
            }
#pragma unroll
            for (int fi = 0; fi < 2; ++fi)
#pragma unroll
                for (int fj = 0; fj < 2; ++fj) {
                    accz[fi][fj]  = __builtin_amdgcn_mfma_f32_16x16x32_bf16(af[fi], bz[fj],  accz[fi][fj],  0, 0, 0);
                    accza[fi][fj] = __builtin_amdgcn_mfma_f32_16x16x32_bf16(af[fi], bza[fj], accza[fi][fj], 0, 0, 0);
                }
            __syncthreads();
            cur ^= 1;
        }
#undef Z_LOAD
#undef Z_WRITE

        const bool first = (rblk & 15) == 0;       // rows l in [0,64): contains l<=h and diag
        const int b8 = (rblk >> 4) * 8;
#pragma unroll
        for (int fj = 0; fj < 2; ++fj) {
            float lsum = 0.f;
            int lc = wn * 32 + fj * 16 + (lane & 15);
            int col = col0 + lc;
            float Bz = b_z[col], Bza = b_za[col];
#pragma unroll
            for (int fi = 0; fi < 2; ++fi) {
#pragma unroll
                for (int q = 0; q < 4; ++q) {
                    int lr = wm * 32 + fi * 16 + ((lane >> 4) << 2) + q;
                    float pz = accz[fi][fj][q] + Bz;
                    float pza = accza[fi][fj][q] + Bza;
                    float v = pz * siluf_(pza);
                    if (!first || lr > bx) lsum += v;
                    if (first && lr == bx) zdiag[(b8 + bx) * 64 + lc] = v;
                }
            }
            red[lc][wm * 4 + (lane >> 4)] = lsum;
        }
        __syncthreads();
        if (tid < 64) {
            float s = 0.f;
#pragma unroll
            for (int j = 0; j < 8; ++j) s += red[tid][j];
            Zs_part[((size_t)rblk * 8 + bx) * 64 + tid] = s;   // race-free partials
        }
    } else {
        // ================= ya family (gate) =================
        const unsigned short* gWya = Wya + (size_t)(col0 + sr_) * 512 + sc_ * 8;
        f32x4 accya[2][2];
#pragma unroll
        for (int a = 0; a < 2; ++a)
#pragma unroll
            for (int bq = 0; bq < 2; ++bq) accya[a][bq] = zf;

        int4 rxa, rya;
#define Y_LOAD(K) { rxa = *(const int4*)(gXa + (K)); rya = *(const int4*)(gWya + (K)); }
#define Y_WRITE(BUF) { *(int4*)((char*)As[BUF] + sld) = rxa; \
                       *(int4*)((char*)Bs[BUF][0] + sld) = rya; }

        Y_LOAD(0);
        Y_WRITE(0);
        Y_LOAD(32);
        __syncthreads();

        int cur = 0;
        for (int s = 0; s < 16; ++s) {
            if (s < 15) {
                Y_WRITE(cur ^ 1);
                if (s < 14) Y_LOAD((s + 2) * 32);
            }
            short8 af[2], bya[2];
#pragma unroll
            for (int fi = 0; fi < 2; ++fi) {
                int rr = wm * 32 + fi * 16 + (lane & 15);
                af[fi] = *(const short8*)((const char*)As[cur] + rr * RS + ck);
            }
#pragma unroll
            for (int fj = 0; fj < 2; ++fj) {
                int rr = wn * 32 + fj * 16 + (lane & 15);
                bya[fj] = *(const short8*)((const char*)Bs[cur][0] + rr * RS + ck);
            }
#pragma unroll
            for (int fi = 0; fi < 2; ++fi)
#pragma unroll
                for (int fj = 0; fj < 2; ++fj)
                    accya[fi][fj] = __builtin_amdgcn_mfma_f32_16x16x32_bf16(af[fi], bya[fj], accya[fi][fj], 0, 0, 0);
            __syncthreads();
            cur ^= 1;
        }
#undef Y_LOAD
#undef Y_WRITE

#pragma unroll
        for (int fj = 0; fj < 2; ++fj) {
            int lc = wn * 32 + fj * 16 + (lane & 15);
            int col = col0 + lc;
            float Bya = b_ya[col];
#pragma unroll
            for (int fi = 0; fi < 2; ++fi)
#pragma unroll
                for (int q = 0; q < 4; ++q) {
                    int lr = wm * 32 + fi * 16 + ((lane >> 4) << 2) + q;
                    int row = row0 + lr;
                    gateb[(size_t)row * 512 + col] = f2bf(siluf_(accya[fi][fj][q] + Bya));
                }
        }
    }
}

// ========== K3: 32-row blocks (3 blocks/CU): inline hgn -> LDS bf16 + reg-pipelined gemm_y ====
// grid = 512: cbx = bid&7 (same-Wy-panel per XCD), rsub = bid>>3 (0..63), row0 = rsub*32.
__global__ __launch_bounds__(256) void k3_hgn_gemm_y(
    const unsigned short* __restrict__ Wy, const float* __restrict__ b_y,
    const unsigned short* __restrict__ gateb,
    const float* __restrict__ Sr, const float* __restrict__ Si,
    const float* __restrict__ Zs_part, const float* __restrict__ zdiag,
    const float* __restrict__ lc_r, const float* __restrict__ lc_i,
    const float* __restrict__ gn_w, const float* __restrict__ gn_b,
    float* __restrict__ y)
{
    __shared__ unsigned short hA[32][520];          // 1040B row stride (period-8 slot cycle)
    __shared__ short Bs[2][64 * RSS];
    __shared__ float Cr[8][65], Ci[8][65], Zd[8][65];
    const int tid = threadIdx.x;
    const int lane = tid & 63, w = tid >> 6;
    const int cbx = blockIdx.x & 7;
    const int rsub = blockIdx.x >> 3;               // 0..63
    const int row0 = rsub * 32, col0 = cbx * 64;
    const int b = row0 >> 10;                       // L_=1024

    // ---- prologue: issue Wy tiles 0 and 1 into regs; latency hides under hgn phase ----
    const int brow = tid >> 2, bsc = tid & 3;       // 64 rows x 4 chunks of 16B
    const size_t gB = (size_t)(col0 + brow) * 512 + bsc * 8;
    const int bwr = brow * RS + bsc * 16;
    int4 rw0 = *(const int4*)(Wy + gB);
    int4 rw1 = *(const int4*)(Wy + gB + 32);

    // ---- stage per-(h,i) constants: Zs (reduced from partials) + lc, zdiag ----
    for (int uu = tid; uu < 512; uu += 256) {
        int h = uu >> 6, i = uu & 63;
        float s = 0.f;
#pragma unroll
        for (int rb = 0; rb < 16; ++rb)
            s += Zs_part[(((size_t)b * 16 + rb) * 8 + h) * 64 + i];
        Cr[h][i] = s + lc_r[h * 64 + i];
        Ci[h][i] = lc_i[h * 64 + i];
        Zd[h][i] = zdiag[((size_t)b * 8 + h) * 64 + i];
    }
    __syncthreads();

    // ---- phase 1: h + GroupNorm, one (row, head) per thread, write bf16 into hA ----
    {
        const int r = tid >> 3, h = tid & 7;        // r in 0..31
        const int row = row0 + r;
        const float sr = Sr[(size_t)row * 8 + h];
        const float si = Si[(size_t)row * 8 + h];
        const float er = expf(sr);
        const float ca = er * cosf(si), sb = er * sinf(si);
        float sum = 0.f, sq = 0.f;
#pragma unroll 8
        for (int i = 0; i < 64; ++i) {
            float hv = Zd[h][i] + ca * Cr[h][i] - sb * Ci[h][i];
            sum += hv; sq += hv * hv;
        }
        const float mean = sum * (1.f / 64.f);
        const float inv = rsqrtf(sq * (1.f / 64.f) - mean * mean + 1e-5f);
        const float gw = gn_w[h] * inv;
        const float gb = gn_b[h] - mean * gw;
#pragma unroll
        for (int s8 = 0; s8 < 8; ++s8) {
            short8 pk;
#pragma unroll
            for (int j = 0; j < 8; ++j) {
                int i = s8 * 8 + j;
                float hv = Zd[h][i] + ca * Cr[h][i] - sb * Ci[h][i];
                pk[j] = (short)f2bf(hv * gw + gb);
            }
            int slot = (s8 + h) & 7;   // per-head slot rotation: conflict-free writes
            *(short8*)((char*)&hA[r][0] + h * 128 + slot * 16) = pk;
        }
    }
    *(int4*)((char*)Bs[0] + bwr) = rw0;             // stage Wy tile 0
    __syncthreads();

    // ---- phase 2: y = (hA @ Wy^T(bf16) + b_y) * gate, reg-pipelined Wy, 4 col-quarter waves --
    const f32x4 zf = {0.f, 0.f, 0.f, 0.f};
    f32x4 acc[2] = {zf, zf};

    int cur = 0;
    for (int s = 0; s < 16; ++s) {
        if (s < 15) {
            *(int4*)((char*)Bs[cur ^ 1] + bwr) = rw1;               // stage tile s+1
            if (s < 14) rw1 = *(const int4*)(Wy + gB + (s + 2) * 32);   // prefetch s+2
        }
        const int k0 = s * 32;
        short8 af[2], bf;
        const int hk = k0 >> 6;
        const int t = ((k0 & 32) >> 3) + (lane >> 4);
        const int slot = (t + hk) & 7;              // undo phase-1 rotation
#pragma unroll
        for (int fi = 0; fi < 2; ++fi) {
            int rr = fi * 16 + (lane & 15);
            af[fi] = *(const short8*)((const char*)&hA[rr][0] + hk * 128 + slot * 16);
        }
        {
            int rr = w * 16 + (lane & 15);
            bf = *(const short8*)((const char*)Bs[cur] + rr * RS + ((lane >> 4) << 4));
        }
        acc[0] = __builtin_amdgcn_mfma_f32_16x16x32_bf16(af[0], bf, acc[0], 0, 0, 0);
        acc[1] = __builtin_amdgcn_mfma_f32_16x16x32_bf16(af[1], bf, acc[1], 0, 0, 0);
        __syncthreads();
        cur ^= 1;
    }

    const int col = col0 + w * 16 + (lane & 15);
    const float By = b_y[col];
#pragma unroll
    for (int fi = 0; fi < 2; ++fi)
#pragma unroll
        for (int q = 0; q < 4; ++q) {
            int row = row0 + fi * 16 + ((lane >> 4) << 2) + q;
            size_t idx = (size_t)row * 512 + col;
            y[idx] = (acc[fi][q] + By) * bf2f(gateb[idx]);
        }
}

extern "C" void kernel_launch(void* const* d_in, const int* in_sizes, int n_in,
                              void* d_out, int out_size, void* d_ws, size_t ws_size,
                              hipStream_t stream) {
    (void)n_in; (void)out_size; (void)ws_size;
    const float* x     = (const float*)d_in[0];
    const float* w_z   = (const float*)d_in[1];
    const float* b_z   = (const float*)d_in[2];
    const float* w_za  = (const float*)d_in[3];
    const float* b_za  = (const float*)d_in[4];
    const float* w_ang = (const float*)d_in[5];
    const float* b_ang = (const float*)d_in[6];
    const float* w_abs = (const float*)d_in[7];
    const float* b_abs = (const float*)d_in[8];
    const float* w_y   = (const float*)d_in[9];
    const float* b_y   = (const float*)d_in[10];
    const float* w_ya  = (const float*)d_in[11];
    const float* b_ya  = (const float*)d_in[12];
    const float* gn_w  = (const float*)d_in[13];
    const float* gn_b  = (const float*)d_in[14];
    const float* lc_r  = (const float*)d_in[15];
    const float* lc_i  = (const float*)d_in[16];
    float* y = (float*)d_out;

    const int BL = in_sizes[0] / D_;   // 2048
    const int B  = BL / L_;            // 2

    unsigned short* wtz  = (unsigned short*)d_ws;            // 512*512 each
    unsigned short* wtza = wtz  + 512 * 512;
    unsigned short* wtya = wtza + 512 * 512;
    unsigned short* wty  = wtya + 512 * 512;
    unsigned short* gateb= wty  + 512 * 512;                 // BL*512
    unsigned short* xb   = gateb + (size_t)BL * 512;         // BL*512 bf16
    float* a_arr = (float*)(xb + (size_t)BL * 512);          // BL*H
    float* r_arr = a_arr + (size_t)BL * H_;
    float* Si    = r_arr + (size_t)BL * H_;
    float* Sr    = Si    + (size_t)BL * H_;
    float* zdiag = Sr    + (size_t)BL * H_;                  // B*H*I
    float* Zs_part = zdiag + (size_t)B * H_ * I_;            // (BL/64)*H*I

    const int ntiles = (BL / 64) * 8;       // 256

    k1_prep<<<256 + BL / 4, 256, 0, stream>>>(
        x, xb, w_z, w_za, w_ya, w_y, wtz, wtza, wtya, wty,
        w_ang, b_ang, w_abs, b_abs, a_arr, r_arr);
    k2_split<<<16 + 2 * ntiles, 256, 0, stream>>>(
        xb, wtz, wtza, wtya, b_z, b_za, b_ya,
        gateb, Zs_part, zdiag, a_arr, r_arr, Si, Sr);
    k3_hgn_gemm_y<<<2 * ntiles, 256, 0, stream>>>(
        wty, b_y, gateb, Sr, Si, Zs_part, zdiag, lc_r, lc_i, gn_w, gn_b, y);
}